// Round 4
// baseline (210.527 us; speedup 1.0000x reference)
//
#include <hip/hip_runtime.h>

typedef unsigned short u16;
typedef __attribute__((ext_vector_type(8))) short short8;
typedef __attribute__((ext_vector_type(4))) float f32x4;

// ---------- helpers ----------
__device__ inline u16 f2bf(float f) {
    union { float f; unsigned u; } v; v.f = f;
    unsigned u = v.u;
    unsigned r = (u + 0x7FFFu + ((u >> 16) & 1u)) >> 16;
    return (u16)r;
}
__device__ inline float bf2f(u16 h) {
    union { unsigned u; float f; } v; v.u = ((unsigned)h) << 16;
    return v.f;
}
__device__ inline float ftanh(float x) {
    float e = __expf(2.f * x);
    return 1.f - 2.f / (e + 1.f);
}

// ---------- kernel 1: mask + bf16 cast + row norms; tail blocks do W transpose ----------
__global__ __launch_bounds__(128) void prep_kernel(
    const float* __restrict__ F0r, const float* __restrict__ F1r,
    const float* __restrict__ m0, const float* __restrict__ m1,
    const float* __restrict__ W0, const float* __restrict__ W1,
    u16* __restrict__ F0b, u16* __restrict__ F1b,
    u16* __restrict__ WT0, u16* __restrict__ WT1,
    float* __restrict__ sq0, float* __restrict__ sq1)
{
    int bx = blockIdx.x;
    int t = threadIdx.x;
    if (bx >= 16384) {
        // W [S,D] fp32 -> WT [D,S] bf16  (2*131072 elements, 2048 blocks)
        int idx = (bx - 16384) * 128 + t;
        int a = idx >> 17;
        int r = idx & 131071;
        int s = r >> 9, d = r & 511;
        const float* W = a ? W1 : W0;
        u16* WT = a ? WT1 : WT0;
        WT[d * 256 + s] = f2bf(W[r]);
        return;
    }
    int bs = bx;                  // b*256 + s
    size_t base = (size_t)bs * 512 + t * 4;
    float mk0 = m0[bs], mk1 = m1[bs];
    float4 v0 = *(const float4*)(F0r + base);
    float4 v1 = *(const float4*)(F1r + base);
    v0.x *= mk0; v0.y *= mk0; v0.z *= mk0; v0.w *= mk0;
    v1.x *= mk1; v1.y *= mk1; v1.z *= mk1; v1.w *= mk1;
    ushort4 u0; u0.x = f2bf(v0.x); u0.y = f2bf(v0.y); u0.z = f2bf(v0.z); u0.w = f2bf(v0.w);
    ushort4 u1; u1.x = f2bf(v1.x); u1.y = f2bf(v1.y); u1.z = f2bf(v1.z); u1.w = f2bf(v1.w);
    *(ushort4*)(F0b + base) = u0;
    *(ushort4*)(F1b + base) = u1;
    float s0p = v0.x*v0.x + v0.y*v0.y + v0.z*v0.z + v0.w*v0.w;
    float s1p = v1.x*v1.x + v1.y*v1.y + v1.z*v1.z + v1.w*v1.w;
    #pragma unroll
    for (int off = 32; off > 0; off >>= 1) {
        s0p += __shfl_xor(s0p, off);
        s1p += __shfl_xor(s1p, off);
    }
    __shared__ float red0[2], red1[2];
    if ((t & 63) == 0) { red0[t >> 6] = s0p; red1[t >> 6] = s1p; }
    __syncthreads();
    if (t == 0) { sq0[bs] = red0[0] + red0[1]; sq1[bs] = red1[0] + red1[1]; }
}

// ---------- kernel 2: cross-GEMM (64x64 tile, K=512, chunk 128); writes A and A^T ----------
__global__ __launch_bounds__(256) void gemm_cross_kernel(
    const u16* __restrict__ F0b, const u16* __restrict__ F1b,
    const float* __restrict__ sq0, const float* __restrict__ sq1,
    u16* __restrict__ Abf, u16* __restrict__ ATbf)
{
    __shared__ __align__(16) u16 smem[64 * 136 * 2];   // As | Bs, 34.8 KB
    u16 (*As)[136] = (u16(*)[136])smem;
    u16 (*Bs)[136] = (u16(*)[136])(smem + 64 * 136);

    int b = blockIdx.y;
    int i0 = (blockIdx.x >> 2) * 64, j0 = (blockIdx.x & 3) * 64;
    const u16* Ap = F0b + (size_t)b * 131072;
    const u16* Bp = F1b + (size_t)b * 131072;
    const float* sqR = sq0 + b * 256;
    const float* sqC = sq1 + b * 256;

    const int t = threadIdx.x;
    const int lane = t & 63, w = t >> 6;
    const int wm = w >> 1, wn = w & 1;
    const int q = lane >> 4, lm = lane & 15;

    f32x4 acc[2][2];
    #pragma unroll
    for (int x = 0; x < 2; ++x)
        #pragma unroll
        for (int y = 0; y < 2; ++y)
            acc[x][y] = (f32x4){0.f, 0.f, 0.f, 0.f};

    for (int k0 = 0; k0 < 512; k0 += 128) {
        #pragma unroll
        for (int i = 0; i < 4; ++i) {
            int idx = i * 256 + t;       // 0..1023
            int row = idx >> 4;          // 0..63
            int seg = idx & 15;          // 16 segs of 8 bf16 per 128-k row
            *(uint4*)&As[row][seg * 8] =
                *(const uint4*)(Ap + (size_t)(i0 + row) * 512 + k0 + seg * 8);
            *(uint4*)&Bs[row][seg * 8] =
                *(const uint4*)(Bp + (size_t)(j0 + row) * 512 + k0 + seg * 8);
        }
        __syncthreads();
        #pragma unroll
        for (int ks = 0; ks < 128; ks += 32) {
            short8 af[2], bfr[2];
            #pragma unroll
            for (int x = 0; x < 2; ++x) {
                af[x]  = *(const short8*)&As[wm * 32 + x * 16 + lm][ks + q * 8];
                bfr[x] = *(const short8*)&Bs[wn * 32 + x * 16 + lm][ks + q * 8];
            }
            #pragma unroll
            for (int x = 0; x < 2; ++x)
                #pragma unroll
                for (int y = 0; y < 2; ++y)
                    acc[x][y] = __builtin_amdgcn_mfma_f32_16x16x32_bf16(
                        af[x], bfr[y], acc[x][y], 0, 0, 0);
        }
        __syncthreads();
    }

    // epilogue: A values into LDS tile (alias As), then vectorized A and A^T stores
    u16 (*Ct)[136] = (u16(*)[136])smem;
    #pragma unroll
    for (int x = 0; x < 2; ++x) {
        #pragma unroll
        for (int r = 0; r < 4; ++r) {
            int ir = wm * 32 + x * 16 + q * 4 + r;
            float si = sqR[i0 + ir];
            #pragma unroll
            for (int y = 0; y < 2; ++y) {
                int jc = wn * 32 + y * 16 + lm;
                float d2 = si + sqC[j0 + jc] - 2.f * acc[x][y][r];
                d2 = fmaxf(d2, 0.f);
                float a = 1.f / (1.f + sqrtf(d2));
                Ct[ir][jc] = f2bf(a);
            }
        }
    }
    __syncthreads();

    u16* Aout  = Abf  + (size_t)b * 65536;
    u16* ATout = ATbf + (size_t)b * 65536;
    int ii = t >> 2;              // 0..63
    int c0 = (t & 3) * 16;        // 0,16,32,48
    #pragma unroll
    for (int c = 0; c < 4; ++c) { // A: row-major, vectorized
        ushort4 v = *(ushort4*)&Ct[ii][c0 + c * 4];
        *(ushort4*)&Aout[(size_t)(i0 + ii) * 256 + j0 + c0 + c * 4] = v;
    }
    #pragma unroll
    for (int c = 0; c < 4; ++c) { // A^T: transpose-read from LDS
        ushort4 v;
        v.x = Ct[c0 + c * 4 + 0][ii];
        v.y = Ct[c0 + c * 4 + 1][ii];
        v.z = Ct[c0 + c * 4 + 2][ii];
        v.w = Ct[c0 + c * 4 + 3][ii];
        *(ushort4*)&ATout[(size_t)(j0 + ii) * 256 + i0 + c0 + c * 4] = v;
    }
}

// ---------- kernel 3: Fa GEMMs, 64(rows)x128(d) tile, K=256 chunk 64 ----------
// var 0: F0a[j][d] = sum_i AT[j][i] * WT0[d][i];  var 1: F1a[i][d] = sum_j A[i][j] * WT1[d][j]
__global__ __launch_bounds__(256) void gemm_fa_kernel(
    const u16* __restrict__ Abf, const u16* __restrict__ ATbf,
    const u16* __restrict__ WT0, const u16* __restrict__ WT1,
    u16* __restrict__ F0a, u16* __restrict__ F1a)
{
    __shared__ __align__(16) u16 smem[64 * 72 + 128 * 72];   // As | Bs, 27.6 KB
    u16 (*As)[72] = (u16(*)[72])smem;
    u16 (*Bs)[72] = (u16(*)[72])(smem + 64 * 72);

    int b = blockIdx.y, var = blockIdx.z;
    int m0 = (blockIdx.x >> 2) * 64;    // row tile, 0..192
    int n0 = (blockIdx.x & 3) * 128;    // d tile, 0..384
    const u16 *Ap, *Bp; u16* Out;
    if (var == 0) { Ap = ATbf + (size_t)b * 65536; Bp = WT0; Out = F0a + (size_t)b * 131072; }
    else          { Ap = Abf  + (size_t)b * 65536; Bp = WT1; Out = F1a + (size_t)b * 131072; }

    const int t = threadIdx.x;
    const int lane = t & 63, w = t >> 6;
    const int wm = w >> 1, wn = w & 1;    // wave covers rows wm*32.., cols wn*64..
    const int q = lane >> 4, lm = lane & 15;

    f32x4 acc[2][4];
    #pragma unroll
    for (int x = 0; x < 2; ++x)
        #pragma unroll
        for (int y = 0; y < 4; ++y)
            acc[x][y] = (f32x4){0.f, 0.f, 0.f, 0.f};

    for (int k0 = 0; k0 < 256; k0 += 64) {
        #pragma unroll
        for (int i = 0; i < 6; ++i) {
            int idx = i * 256 + t;       // 0..1535 -> 192 rows x 8 segs
            int row = idx >> 3;
            int seg = idx & 7;
            uint4 v;
            if (row < 64)
                v = *(const uint4*)(Ap + (size_t)(m0 + row) * 256 + k0 + seg * 8);
            else
                v = *(const uint4*)(Bp + (size_t)(n0 + row - 64) * 256 + k0 + seg * 8);
            if (row < 64) *(uint4*)&As[row][seg * 8] = v;
            else          *(uint4*)&Bs[row - 64][seg * 8] = v;
        }
        __syncthreads();
        #pragma unroll
        for (int ks = 0; ks < 64; ks += 32) {
            short8 af[2], bfr[4];
            #pragma unroll
            for (int x = 0; x < 2; ++x)
                af[x] = *(const short8*)&As[wm * 32 + x * 16 + lm][ks + q * 8];
            #pragma unroll
            for (int y = 0; y < 4; ++y)
                bfr[y] = *(const short8*)&Bs[wn * 64 + y * 16 + lm][ks + q * 8];
            #pragma unroll
            for (int x = 0; x < 2; ++x)
                #pragma unroll
                for (int y = 0; y < 4; ++y)
                    acc[x][y] = __builtin_amdgcn_mfma_f32_16x16x32_bf16(
                        af[x], bfr[y], acc[x][y], 0, 0, 0);
        }
        __syncthreads();
    }

    // epilogue: pack to LDS (alias smem as [64][136]), then ushort4 stores
    u16 (*Ct)[136] = (u16(*)[136])smem;
    #pragma unroll
    for (int x = 0; x < 2; ++x)
        #pragma unroll
        for (int r = 0; r < 4; ++r) {
            int ir = wm * 32 + x * 16 + q * 4 + r;
            #pragma unroll
            for (int y = 0; y < 4; ++y) {
                int jc = wn * 64 + y * 16 + lm;
                Ct[ir][jc] = f2bf(acc[x][y][r]);
            }
        }
    __syncthreads();
    int ii = t >> 2;              // 0..63
    int c0 = (t & 3) * 32;        // 0,32,64,96
    #pragma unroll
    for (int c = 0; c < 8; ++c) {
        ushort4 v = *(ushort4*)&Ct[ii][c0 + c * 4];
        *(ushort4*)&Out[(size_t)(m0 + ii) * 512 + n0 + c0 + c * 4] = v;
    }
}

// ---------- kernel 4: conv(2ch,3x1) + tanh + avgpool(3x1), all-bf16 inputs ----------
__device__ inline void load_row_cv(
    const u16* __restrict__ Fb, const u16* __restrict__ Fa,
    int s, int d0, float4& f, float4& a)
{
    if ((unsigned)s < 256u) {
        ushort4 uf = *(const ushort4*)(Fb + (size_t)s * 512 + d0);
        ushort4 ua = *(const ushort4*)(Fa + (size_t)s * 512 + d0);
        f.x = bf2f(uf.x); f.y = bf2f(uf.y); f.z = bf2f(uf.z); f.w = bf2f(uf.w);
        a.x = bf2f(ua.x); a.y = bf2f(ua.y); a.z = bf2f(ua.z); a.w = bf2f(ua.w);
    } else {
        f = make_float4(0.f, 0.f, 0.f, 0.f);
        a = make_float4(0.f, 0.f, 0.f, 0.f);
    }
}

__global__ __launch_bounds__(128) void conv_kernel(
    const u16* __restrict__ F0b, const u16* __restrict__ F1b,
    const u16* __restrict__ F0a, const u16* __restrict__ F1a,
    const float* __restrict__ cw, const float* __restrict__ cb,
    float* __restrict__ out)
{
    int b = blockIdx.y;
    int which = blockIdx.z;
    int s0 = blockIdx.x * 16;
    int d0 = threadIdx.x * 4;
    const u16* Fb = (which ? F1b : F0b) + (size_t)b * 131072;
    const u16* Fa = (which ? F1a : F0a) + (size_t)b * 131072;
    float* o = out + (size_t)which * 8388608 + (size_t)b * 131072 + d0;
    float w00 = cw[0], w01 = cw[1], w02 = cw[2];
    float w10 = cw[3], w11 = cw[4], w12 = cw[5];
    float bias = cb[0];

    float4 fm2, fm1, fc, fp1, fp2, am2, am1, ac, ap1, ap2;
    load_row_cv(Fb, Fa, s0 - 2, d0, fm2, am2);
    load_row_cv(Fb, Fa, s0 - 1, d0, fm1, am1);
    load_row_cv(Fb, Fa, s0,     d0, fc,  ac);
    load_row_cv(Fb, Fa, s0 + 1, d0, fp1, ap1);
    load_row_cv(Fb, Fa, s0 + 2, d0, fp2, ap2);

    #define CONV_Y(Y, F0_, F1_, F2_, A0_, A1_, A2_)                                \
        { Y.x = bias + w00*F0_.x + w01*F1_.x + w02*F2_.x + w10*A0_.x + w11*A1_.x + w12*A2_.x; \
          Y.y = bias + w00*F0_.y + w01*F1_.y + w02*F2_.y + w10*A0_.y + w11*A1_.y + w12*A2_.y; \
          Y.z = bias + w00*F0_.z + w01*F1_.z + w02*F2_.z + w10*A0_.z + w11*A1_.z + w12*A2_.z; \
          Y.w = bias + w00*F0_.w + w01*F1_.w + w02*F2_.w + w10*A0_.w + w11*A1_.w + w12*A2_.w; }
    #define TANH4(Y) { Y.x = ftanh(Y.x); Y.y = ftanh(Y.y); Y.z = ftanh(Y.z); Y.w = ftanh(Y.w); }

    float4 ty0, ty1;
    CONV_Y(ty0, fm2, fm1, fc, am2, am1, ac); TANH4(ty0);
    CONV_Y(ty1, fm1, fc, fp1, am1, ac, ap1); TANH4(ty1);

    float4 w0f = fc, w1f = fp1, w2f = fp2;
    float4 w0a = ac, w1a = ap1, w2a = ap2;
    const float third = 1.f / 3.f;
    for (int s = s0; s < s0 + 16; ++s) {
        float4 ty2;
        CONV_Y(ty2, w0f, w1f, w2f, w0a, w1a, w2a); TANH4(ty2);
        float4 r;
        r.x = (ty0.x + ty1.x + ty2.x) * third;
        r.y = (ty0.y + ty1.y + ty2.y) * third;
        r.z = (ty0.z + ty1.z + ty2.z) * third;
        r.w = (ty0.w + ty1.w + ty2.w) * third;
        *(float4*)(o + (size_t)s * 512) = r;
        ty0 = ty1; ty1 = ty2;
        w0f = w1f; w1f = w2f;
        w0a = w1a; w1a = w2a;
        load_row_cv(Fb, Fa, s + 3, d0, w2f, w2a);
    }
    #undef CONV_Y
    #undef TANH4
}

// ---------- launcher ----------
extern "C" void kernel_launch(void* const* d_in, const int* in_sizes, int n_in,
                              void* d_out, int out_size, void* d_ws, size_t ws_size,
                              hipStream_t stream)
{
    const float* F0r = (const float*)d_in[0];
    const float* F1r = (const float*)d_in[1];
    const float* m0  = (const float*)d_in[2];
    const float* m1  = (const float*)d_in[3];
    const float* W0  = (const float*)d_in[4];
    const float* W1  = (const float*)d_in[5];
    const float* cw  = (const float*)d_in[6];
    const float* cb  = (const float*)d_in[7];
    float* out = (float*)d_out;

    char* ws = (char*)d_ws;
    u16* F0b   = (u16*)(ws);                      // 16 MiB  [B,S,D] bf16
    u16* F1b   = (u16*)(ws + 16777216);           // 16 MiB
    u16* F0a   = (u16*)(ws + 33554432);           // 16 MiB  (separate: conv reads F bf16 too)
    u16* F1a   = (u16*)(ws + 50331648);           // 16 MiB
    u16* Abf   = (u16*)(ws + 67108864);           // 8 MiB   [B,S,S] bf16
    u16* ATbf  = (u16*)(ws + 75497472);           // 8 MiB
    float* sq0 = (float*)(ws + 83886080);         // 64 KiB
    float* sq1 = (float*)(ws + 83951616);         // 64 KiB
    u16* WT0   = (u16*)(ws + 84017152);           // 256 KiB [D,S] bf16
    u16* WT1   = (u16*)(ws + 84279296);           // 256 KiB

    prep_kernel<<<18432, 128, 0, stream>>>(F0r, F1r, m0, m1, W0, W1,
                                           F0b, F1b, WT0, WT1, sq0, sq1);
    gemm_cross_kernel<<<dim3(16, 64), 256, 0, stream>>>(F0b, F1b, sq0, sq1, Abf, ATbf);
    gemm_fa_kernel<<<dim3(16, 64, 2), 256, 0, stream>>>(Abf, ATbf, WT0, WT1, F0a, F1a);
    conv_kernel<<<dim3(16, 64, 2), 128, 0, stream>>>(F0b, F1b, F0a, F1a, cw, cb, out);
}

// Round 5
// 201.424 us; speedup vs baseline: 1.0452x; 1.0452x over previous
//
#include <hip/hip_runtime.h>

typedef unsigned short u16;
typedef __attribute__((ext_vector_type(8))) short short8;
typedef __attribute__((ext_vector_type(4))) float f32x4;

// ---------- helpers ----------
__device__ inline u16 f2bf(float f) {
    union { float f; unsigned u; } v; v.f = f;
    unsigned u = v.u;
    unsigned r = (u + 0x7FFFu + ((u >> 16) & 1u)) >> 16;
    return (u16)r;
}
__device__ inline float bf2f(u16 h) {
    union { unsigned u; float f; } v; v.u = ((unsigned)h) << 16;
    return v.f;
}
__device__ inline float ftanh(float x) {
    float e = __expf(2.f * x);
    return 1.f - 2.f / (e + 1.f);
}
__device__ inline float4 bf4f(ushort4 u) {
    float4 f; f.x = bf2f(u.x); f.y = bf2f(u.y); f.z = bf2f(u.z); f.w = bf2f(u.w);
    return f;
}

// ---------- kernel 1: mask + bf16 cast + row norms; tail blocks do W transpose ----------
__global__ __launch_bounds__(128) void prep_kernel(
    const float* __restrict__ F0r, const float* __restrict__ F1r,
    const float* __restrict__ m0, const float* __restrict__ m1,
    const float* __restrict__ W0, const float* __restrict__ W1,
    u16* __restrict__ F0b, u16* __restrict__ F1b,
    u16* __restrict__ WT0, u16* __restrict__ WT1,
    float* __restrict__ sq0, float* __restrict__ sq1)
{
    int bx = blockIdx.x;
    int t = threadIdx.x;
    if (bx >= 16384) {
        // W [S,D] fp32 -> WT [D,S] bf16  (2*131072 elements, 2048 blocks)
        int idx = (bx - 16384) * 128 + t;
        int a = idx >> 17;
        int r = idx & 131071;
        int s = r >> 9, d = r & 511;
        const float* W = a ? W1 : W0;
        u16* WT = a ? WT1 : WT0;
        WT[d * 256 + s] = f2bf(W[r]);
        return;
    }
    int bs = bx;                  // b*256 + s
    size_t base = (size_t)bs * 512 + t * 4;
    float mk0 = m0[bs], mk1 = m1[bs];
    float4 v0 = *(const float4*)(F0r + base);
    float4 v1 = *(const float4*)(F1r + base);
    v0.x *= mk0; v0.y *= mk0; v0.z *= mk0; v0.w *= mk0;
    v1.x *= mk1; v1.y *= mk1; v1.z *= mk1; v1.w *= mk1;
    ushort4 u0; u0.x = f2bf(v0.x); u0.y = f2bf(v0.y); u0.z = f2bf(v0.z); u0.w = f2bf(v0.w);
    ushort4 u1; u1.x = f2bf(v1.x); u1.y = f2bf(v1.y); u1.z = f2bf(v1.z); u1.w = f2bf(v1.w);
    *(ushort4*)(F0b + base) = u0;
    *(ushort4*)(F1b + base) = u1;
    float s0p = v0.x*v0.x + v0.y*v0.y + v0.z*v0.z + v0.w*v0.w;
    float s1p = v1.x*v1.x + v1.y*v1.y + v1.z*v1.z + v1.w*v1.w;
    #pragma unroll
    for (int off = 32; off > 0; off >>= 1) {
        s0p += __shfl_xor(s0p, off);
        s1p += __shfl_xor(s1p, off);
    }
    __shared__ float red0[2], red1[2];
    if ((t & 63) == 0) { red0[t >> 6] = s0p; red1[t >> 6] = s1p; }
    __syncthreads();
    if (t == 0) { sq0[bs] = red0[0] + red0[1]; sq1[bs] = red1[0] + red1[1]; }
}

// ---------- kernel 2: cross-GEMM (64x64 tile, K=512, chunk 128); writes A and A^T ----------
__global__ __launch_bounds__(256) void gemm_cross_kernel(
    const u16* __restrict__ F0b, const u16* __restrict__ F1b,
    const float* __restrict__ sq0, const float* __restrict__ sq1,
    u16* __restrict__ Abf, u16* __restrict__ ATbf)
{
    __shared__ __align__(16) u16 smem[64 * 136 * 2];   // As | Bs, 34.8 KB
    u16 (*As)[136] = (u16(*)[136])smem;
    u16 (*Bs)[136] = (u16(*)[136])(smem + 64 * 136);

    int b = blockIdx.y;
    int i0 = (blockIdx.x >> 2) * 64, j0 = (blockIdx.x & 3) * 64;
    const u16* Ap = F0b + (size_t)b * 131072;
    const u16* Bp = F1b + (size_t)b * 131072;
    const float* sqR = sq0 + b * 256;
    const float* sqC = sq1 + b * 256;

    const int t = threadIdx.x;
    const int lane = t & 63, w = t >> 6;
    const int wm = w >> 1, wn = w & 1;
    const int q = lane >> 4, lm = lane & 15;

    f32x4 acc[2][2];
    #pragma unroll
    for (int x = 0; x < 2; ++x)
        #pragma unroll
        for (int y = 0; y < 2; ++y)
            acc[x][y] = (f32x4){0.f, 0.f, 0.f, 0.f};

    for (int k0 = 0; k0 < 512; k0 += 128) {
        #pragma unroll
        for (int i = 0; i < 4; ++i) {
            int idx = i * 256 + t;       // 0..1023
            int row = idx >> 4;          // 0..63
            int seg = idx & 15;          // 16 segs of 8 bf16 per 128-k row
            *(uint4*)&As[row][seg * 8] =
                *(const uint4*)(Ap + (size_t)(i0 + row) * 512 + k0 + seg * 8);
            *(uint4*)&Bs[row][seg * 8] =
                *(const uint4*)(Bp + (size_t)(j0 + row) * 512 + k0 + seg * 8);
        }
        __syncthreads();
        #pragma unroll
        for (int ks = 0; ks < 128; ks += 32) {
            short8 af[2], bfr[2];
            #pragma unroll
            for (int x = 0; x < 2; ++x) {
                af[x]  = *(const short8*)&As[wm * 32 + x * 16 + lm][ks + q * 8];
                bfr[x] = *(const short8*)&Bs[wn * 32 + x * 16 + lm][ks + q * 8];
            }
            #pragma unroll
            for (int x = 0; x < 2; ++x)
                #pragma unroll
                for (int y = 0; y < 2; ++y)
                    acc[x][y] = __builtin_amdgcn_mfma_f32_16x16x32_bf16(
                        af[x], bfr[y], acc[x][y], 0, 0, 0);
        }
        __syncthreads();
    }

    // epilogue: A values into LDS tile (alias As), then vectorized A and A^T stores
    u16 (*Ct)[136] = (u16(*)[136])smem;
    #pragma unroll
    for (int x = 0; x < 2; ++x) {
        #pragma unroll
        for (int r = 0; r < 4; ++r) {
            int ir = wm * 32 + x * 16 + q * 4 + r;
            float si = sqR[i0 + ir];
            #pragma unroll
            for (int y = 0; y < 2; ++y) {
                int jc = wn * 32 + y * 16 + lm;
                float d2 = si + sqC[j0 + jc] - 2.f * acc[x][y][r];
                d2 = fmaxf(d2, 0.f);
                float a = 1.f / (1.f + sqrtf(d2));
                Ct[ir][jc] = f2bf(a);
            }
        }
    }
    __syncthreads();

    u16* Aout  = Abf  + (size_t)b * 65536;
    u16* ATout = ATbf + (size_t)b * 65536;
    int ii = t >> 2;              // 0..63
    int c0 = (t & 3) * 16;        // 0,16,32,48
    #pragma unroll
    for (int c = 0; c < 4; ++c) { // A: row-major, vectorized
        ushort4 v = *(ushort4*)&Ct[ii][c0 + c * 4];
        *(ushort4*)&Aout[(size_t)(i0 + ii) * 256 + j0 + c0 + c * 4] = v;
    }
    #pragma unroll
    for (int c = 0; c < 4; ++c) { // A^T: transpose-read from LDS
        ushort4 v;
        v.x = Ct[c0 + c * 4 + 0][ii];
        v.y = Ct[c0 + c * 4 + 1][ii];
        v.z = Ct[c0 + c * 4 + 2][ii];
        v.w = Ct[c0 + c * 4 + 3][ii];
        *(ushort4*)&ATout[(size_t)(j0 + ii) * 256 + i0 + c0 + c * 4] = v;
    }
}

// ---------- kernel 3: fused Fa-GEMM + conv + tanh + avgpool ----------
// Block: 32 out rows x 512 d, one (batch, side). Fa never hits HBM.
// side 0: Fa[j][d] = sum_i AT[j][i]*WT0[d][i], F = F0b -> out0
// side 1: Fa[i][d] = sum_j A[i][j]*WT1[d][j],  F = F1b -> out1
__global__ __launch_bounds__(256) void fa_conv_kernel(
    const u16* __restrict__ Abf, const u16* __restrict__ ATbf,
    const u16* __restrict__ WT0, const u16* __restrict__ WT1,
    const u16* __restrict__ F0b, const u16* __restrict__ F1b,
    const float* __restrict__ cw, const float* __restrict__ cb,
    float* __restrict__ out)
{
    __shared__ __align__(16) u16 Al[48][264];   // A rows (M=48, 36 used) x K=256
    __shared__ __align__(16) u16 Bl[128][72];   // WT d-rows x 64-k chunk
    __shared__ __align__(16) u16 Fl[36][132];   // Fa staging: 36 rows x 128 d

    int b = blockIdx.y, side = blockIdx.z;
    int s0 = blockIdx.x * 32;
    const u16* Ap = (side ? Abf : ATbf) + (size_t)b * 65536;
    const u16* WT = side ? WT1 : WT0;
    const u16* Fb = (side ? F1b : F0b) + (size_t)b * 131072;
    float* o = out + (size_t)side * 8388608 + (size_t)b * 131072;

    const int t = threadIdx.x;
    const int lane = t & 63, w = t >> 6;
    const int q = lane >> 4, lm = lane & 15;

    // stage A once: rows r=0..47 <-> s = s0-2+r; zero when r>=36 or s OOB
    #pragma unroll
    for (int i = 0; i < 6; ++i) {
        int idx = i * 256 + t;          // 0..1535
        int r = idx >> 5;               // 0..47
        int seg = idx & 31;             // 32 segs of 8 bf16
        int s = s0 - 2 + r;
        uint4 v = {0u, 0u, 0u, 0u};
        if (r < 36 && (unsigned)s < 256u)
            v = *(const uint4*)(Ap + (size_t)s * 256 + seg * 8);
        *(uint4*)&Al[r][seg * 8] = v;
    }

    float w00 = cw[0], w01 = cw[1], w02 = cw[2];
    float w10 = cw[3], w11 = cw[4], w12 = cw[5];
    float bias = cb[0];
    const float third = 1.f / 3.f;
    const int g = t >> 5;               // 0..7: out-row group (4 rows)
    const int dl = (t & 31) * 4;        // d within chunk

    for (int n0 = 0; n0 < 512; n0 += 128) {
        f32x4 acc[3][2];
        #pragma unroll
        for (int x = 0; x < 3; ++x)
            #pragma unroll
            for (int y = 0; y < 2; ++y)
                acc[x][y] = (f32x4){0.f, 0.f, 0.f, 0.f};

        for (int kb = 0; kb < 256; kb += 64) {
            #pragma unroll
            for (int i = 0; i < 4; ++i) {
                int idx = i * 256 + t;   // 0..1023
                int r = idx >> 3;        // 0..127 (d row)
                int seg = idx & 7;
                *(uint4*)&Bl[r][seg * 8] =
                    *(const uint4*)(WT + (size_t)(n0 + r) * 256 + kb + seg * 8);
            }
            __syncthreads();
            #pragma unroll
            for (int ks = 0; ks < 64; ks += 32) {
                short8 af[3], bfr[2];
                #pragma unroll
                for (int x = 0; x < 3; ++x)
                    af[x] = *(const short8*)&Al[x * 16 + lm][kb + ks + q * 8];
                #pragma unroll
                for (int y = 0; y < 2; ++y)
                    bfr[y] = *(const short8*)&Bl[w * 32 + y * 16 + lm][ks + q * 8];
                #pragma unroll
                for (int x = 0; x < 3; ++x)
                    #pragma unroll
                    for (int y = 0; y < 2; ++y)
                        acc[x][y] = __builtin_amdgcn_mfma_f32_16x16x32_bf16(
                            af[x], bfr[y], acc[x][y], 0, 0, 0);
            }
            __syncthreads();
        }

        // stage Fa (bf16) into LDS
        #pragma unroll
        for (int x = 0; x < 3; ++x)
            #pragma unroll
            for (int r = 0; r < 4; ++r) {
                int m = x * 16 + q * 4 + r;
                if (m < 36) {
                    #pragma unroll
                    for (int y = 0; y < 2; ++y)
                        Fl[m][w * 32 + y * 16 + lm] = f2bf(acc[x][y][r]);
                }
            }
        __syncthreads();

        // conv + tanh + avgpool for this 128-d chunk; thread: 4 out rows x 4 d
        float4 f[8], a[8];
        #pragma unroll
        for (int k = 0; k < 8; ++k) {
            int s = s0 + g * 4 - 2 + k;
            if ((unsigned)s < 256u)
                f[k] = bf4f(*(const ushort4*)(Fb + (size_t)s * 512 + n0 + dl));
            else
                f[k] = make_float4(0.f, 0.f, 0.f, 0.f);
            a[k] = bf4f(*(const ushort4*)&Fl[g * 4 + k][dl]);
        }
        float4 ty[6];
        #pragma unroll
        for (int k = 0; k < 6; ++k) {
            float4 y;
            y.x = bias + w00*f[k].x + w01*f[k+1].x + w02*f[k+2].x + w10*a[k].x + w11*a[k+1].x + w12*a[k+2].x;
            y.y = bias + w00*f[k].y + w01*f[k+1].y + w02*f[k+2].y + w10*a[k].y + w11*a[k+1].y + w12*a[k+2].y;
            y.z = bias + w00*f[k].z + w01*f[k+1].z + w02*f[k+2].z + w10*a[k].z + w11*a[k+1].z + w12*a[k+2].z;
            y.w = bias + w00*f[k].w + w01*f[k+1].w + w02*f[k+2].w + w10*a[k].w + w11*a[k+1].w + w12*a[k+2].w;
            y.x = ftanh(y.x); y.y = ftanh(y.y); y.z = ftanh(y.z); y.w = ftanh(y.w);
            ty[k] = y;
        }
        #pragma unroll
        for (int r = 0; r < 4; ++r) {
            float4 res;
            res.x = (ty[r].x + ty[r+1].x + ty[r+2].x) * third;
            res.y = (ty[r].y + ty[r+1].y + ty[r+2].y) * third;
            res.z = (ty[r].z + ty[r+1].z + ty[r+2].z) * third;
            res.w = (ty[r].w + ty[r+1].w + ty[r+2].w) * third;
            *(float4*)(o + (size_t)(s0 + g * 4 + r) * 512 + n0 + dl) = res;
        }
        __syncthreads();   // Fl / Bl reused next d-chunk
    }
}

// ---------- launcher ----------
extern "C" void kernel_launch(void* const* d_in, const int* in_sizes, int n_in,
                              void* d_out, int out_size, void* d_ws, size_t ws_size,
                              hipStream_t stream)
{
    const float* F0r = (const float*)d_in[0];
    const float* F1r = (const float*)d_in[1];
    const float* m0  = (const float*)d_in[2];
    const float* m1  = (const float*)d_in[3];
    const float* W0  = (const float*)d_in[4];
    const float* W1  = (const float*)d_in[5];
    const float* cw  = (const float*)d_in[6];
    const float* cb  = (const float*)d_in[7];
    float* out = (float*)d_out;

    char* ws = (char*)d_ws;
    u16* F0b   = (u16*)(ws);                      // 16 MiB  [B,S,D] bf16
    u16* F1b   = (u16*)(ws + 16777216);           // 16 MiB
    u16* Abf   = (u16*)(ws + 33554432);           // 8 MiB   [B,S,S] bf16
    u16* ATbf  = (u16*)(ws + 41943040);           // 8 MiB
    float* sq0 = (float*)(ws + 50331648);         // 64 KiB
    float* sq1 = (float*)(ws + 50397184);         // 64 KiB
    u16* WT0   = (u16*)(ws + 50462720);           // 256 KiB [D,S] bf16
    u16* WT1   = (u16*)(ws + 50724864);           // 256 KiB

    prep_kernel<<<18432, 128, 0, stream>>>(F0r, F1r, m0, m1, W0, W1,
                                           F0b, F1b, WT0, WT1, sq0, sq1);
    gemm_cross_kernel<<<dim3(16, 64), 256, 0, stream>>>(F0b, F1b, sq0, sq1, Abf, ATbf);
    fa_conv_kernel<<<dim3(8, 64, 2), 256, 0, stream>>>(Abf, ATbf, WT0, WT1,
                                                       F0b, F1b, cw, cb, out);
}